// Round 1
// baseline (278.812 us; speedup 1.0000x reference)
//
#include <hip/hip_runtime.h>
#include <math.h>

#define NB 32
#define NB2 1024
#define EPS 1e-5f

// Kernel 1: joint histogram via per-block LDS histogram + global atomic flush.
__global__ __launch_bounds__(256) void hist_kernel(const float* __restrict__ I,
                                                   const float* __restrict__ J,
                                                   unsigned int* __restrict__ hist,
                                                   int n4) {
    __shared__ unsigned int lh[NB2];
    const int t = threadIdx.x;
    for (int i = t; i < NB2; i += 256) lh[i] = 0u;
    __syncthreads();

    const float4* __restrict__ I4 = (const float4*)I;
    const float4* __restrict__ J4 = (const float4*)J;
    const int stride = gridDim.x * 256;
    const float s = 31.0f / 255.0f;  // single mul is bit-exact vs /255*31 here:
                                     // true values never within 2e-3 of a .5 boundary

    for (int i = blockIdx.x * 256 + t; i < n4; i += stride) {
        float4 a = I4[i];
        float4 b = J4[i];
        int i0 = (int)rintf(a.x * s), j0 = (int)rintf(b.x * s);
        int i1 = (int)rintf(a.y * s), j1 = (int)rintf(b.y * s);
        int i2 = (int)rintf(a.z * s), j2 = (int)rintf(b.z * s);
        int i3 = (int)rintf(a.w * s), j3 = (int)rintf(b.w * s);
        atomicAdd(&lh[(i0 << 5) | j0], 1u);
        atomicAdd(&lh[(i1 << 5) | j1], 1u);
        atomicAdd(&lh[(i2 << 5) | j2], 1u);
        atomicAdd(&lh[(i3 << 5) | j3], 1u);
    }
    __syncthreads();

    for (int i = t; i < NB2; i += 256) {
        unsigned int c = lh[i];
        if (c) atomicAdd(&hist[i], c);
    }
}

// Kernel 2: probs -> marginals -> MI -> sigmoid(-mi). One block, 1024 threads.
__global__ __launch_bounds__(1024) void mi_kernel(const unsigned int* __restrict__ hist,
                                                  float* __restrict__ out,
                                                  float invN) {
    __shared__ float jp[NB2];
    __shared__ float Ip[NB];
    __shared__ float Jp[NB];
    __shared__ float wsum[16];

    const int t = threadIdx.x;
    float p = (float)hist[t] * invN;  // invN = 2^-25: exact
    jp[t] = p;
    __syncthreads();

    if (t < NB) {  // row sums (marginal over J)
        float acc = 0.0f;
        for (int c = 0; c < NB; ++c) acc += jp[(t << 5) | c];
        Ip[t] = acc;
    } else if (t < 2 * NB) {  // col sums (marginal over I)
        int c = t - NB;
        float acc = 0.0f;
        for (int r = 0; r < NB; ++r) acc += jp[(r << 5) | c];
        Jp[c] = acc;
    }
    __syncthreads();

    float term = p * (logf(p + EPS) - logf(Ip[t >> 5] + EPS) - logf(Jp[t & 31] + EPS));

    // wave-64 shuffle reduce
    for (int off = 32; off > 0; off >>= 1) term += __shfl_down(term, off, 64);
    const int wave = t >> 6;
    if ((t & 63) == 0) wsum[wave] = term;
    __syncthreads();

    if (t == 0) {
        float mi = 0.0f;
        for (int w = 0; w < 16; ++w) mi += wsum[w];
        out[0] = 1.0f / (1.0f + expf(mi));  // sigmoid(-mi)
    }
}

extern "C" void kernel_launch(void* const* d_in, const int* in_sizes, int n_in,
                              void* d_out, int out_size, void* d_ws, size_t ws_size,
                              hipStream_t stream) {
    const float* I = (const float*)d_in[0];
    const float* J = (const float*)d_in[1];
    unsigned int* hist = (unsigned int*)d_ws;  // 4 KiB of workspace
    const int n = in_sizes[0];                 // 33,554,432
    const int n4 = n >> 2;

    hipMemsetAsync(hist, 0, NB2 * sizeof(unsigned int), stream);
    hist_kernel<<<1024, 256, 0, stream>>>(I, J, hist, n4);
    mi_kernel<<<1, 1024, 0, stream>>>(hist, (float*)d_out, 1.0f / (float)n);
}